// Round 5
// baseline (539.847 us; speedup 1.0000x reference)
//
#include <hip/hip_runtime.h>
#include <math.h>

#define FEAT 256
#define RANKK 16
#define PRJ_NODES 16
#define CAND_CAP 131072
#define TIE_CAP 2048
#define NBK_MAX 512   // max buckets (nhe/256)

typedef unsigned long long u64;

static __device__ __forceinline__ u64 pack_pair(unsigned e_low, unsigned bits, unsigned idx) {
    // [63:56]=e&255, [55:26]=score bits (<2^30 since score<=1.0f), [25:0]=idx
    return ((u64)e_low << 56) | ((u64)bits << 26) | (u64)idx;
}

// ---------------- proj = x @ W^T  (double accumulation, f32 output) ----------------
__global__ __launch_bounds__(256) void proj_kernel(const float* __restrict__ x,
        const float* __restrict__ Wm, float* __restrict__ proj, int n_nodes) {
    __shared__ float Ws[RANKK][FEAT + 4];
    __shared__ float Xs[PRJ_NODES][FEAT + 4];
    const float4* x4 = (const float4*)x;
    const float4* w4 = (const float4*)Wm;
    for (int t = threadIdx.x; t < RANKK * (FEAT / 4); t += 256) {
        int r = t >> 6, j4 = t & 63;
        *(float4*)&Ws[r][j4 * 4] = w4[t];
    }
    int nodeBase = blockIdx.x * PRJ_NODES;
    for (int t = threadIdx.x; t < PRJ_NODES * (FEAT / 4); t += 256) {
        int n = t >> 6, j4 = t & 63;
        int node = nodeBase + n;
        float4 v = make_float4(0.f, 0.f, 0.f, 0.f);
        if (node < n_nodes) v = x4[(size_t)node * (FEAT / 4) + j4];
        *(float4*)&Xs[n][j4 * 4] = v;
    }
    __syncthreads();
    int n = threadIdx.x >> 4, r = threadIdx.x & 15;
    int node = nodeBase + n;
    if (node >= n_nodes) return;
    double acc = 0.0;
    #pragma unroll 8
    for (int j4 = 0; j4 < FEAT / 4; ++j4) {
        float4 xv = *(const float4*)&Xs[n][j4 * 4];
        float4 wv = *(const float4*)&Ws[r][j4 * 4];
        acc += (double)xv.x * (double)wv.x + (double)xv.y * (double)wv.y
             + (double)xv.z * (double)wv.z + (double)xv.w * (double)wv.w;
    }
    proj[(size_t)node * RANKK + r] = (float)acc;
}

// ---------------- ef2[e] = ef[edge_ids[e]] ----------------
__global__ void gather_ef(const float4* __restrict__ ef, const int* __restrict__ edge_ids,
                          float4* __restrict__ ef2, int nhe) {
    int t = blockIdx.x * blockDim.x + threadIdx.x;
    if (t >= nhe * 4) return;
    int e = t >> 2, c = t & 3;
    ef2[(size_t)e * 4 + c] = ef[(size_t)edge_ids[e] * 4 + c];
}

// ---------------- bucket histogram of E_idx>>8 ----------------
__global__ void ehist_kernel(const int* __restrict__ E_idx, unsigned* __restrict__ bucketCnt,
                             int nnz, int nb) {
    __shared__ unsigned h[NBK_MAX];
    for (int t = threadIdx.x; t < NBK_MAX; t += blockDim.x) h[t] = 0;
    __syncthreads();
    for (int i = blockIdx.x * blockDim.x + threadIdx.x; i < nnz; i += gridDim.x * blockDim.x)
        atomicAdd(&h[((unsigned)E_idx[i]) >> 8], 1u);
    __syncthreads();
    for (int t = threadIdx.x; t < nb; t += blockDim.x)
        if (h[t]) atomicAdd(&bucketCnt[t], h[t]);
}

// ---------------- exclusive scan over bucket counts ----------------
__global__ void bucket_scan(const unsigned* __restrict__ bucketCnt,
                            unsigned* __restrict__ bucketBase, unsigned* __restrict__ cursor,
                            int nb, int nnz) {
    __shared__ unsigned s[NBK_MAX];
    int t = threadIdx.x;  // NBK_MAX threads
    unsigned c = (t < nb) ? bucketCnt[t] : 0u;
    s[t] = c;
    __syncthreads();
    for (int off = 1; off < NBK_MAX; off <<= 1) {
        unsigned v = (t >= off) ? s[t - off] : 0u;
        __syncthreads();
        s[t] += v;
        __syncthreads();
    }
    unsigned excl = s[t] - c;
    if (t < nb) { bucketBase[t] = excl; cursor[t] = excl; }
    if (t == 0) bucketBase[nb] = (unsigned)nnz;
}

// ---- fused score kernel: gather, f64 dot, sigmoid, store + level-1 histogram ----
__global__ __launch_bounds__(256) void score_kernel(
        const float4* __restrict__ proj4, const float4* __restrict__ ef4,
        const int2* __restrict__ V2, const int2* __restrict__ E2,
        float2* __restrict__ scores2, unsigned* __restrict__ hist1g,
        int npair, int nnz) {
    __shared__ unsigned h[4096];
    for (int t = threadIdx.x; t < 4096; t += 256) h[t] = 0;
    __syncthreads();
    unsigned r1016 = 0, r1015 = 0, r0 = 0;
    int stride = gridDim.x * 256;
    for (int i = blockIdx.x * 256 + threadIdx.x; i < npair; i += stride) {
        int2 v = V2[i];
        int2 e = E2[i];
        float4 a0 = proj4[(size_t)v.x * 4 + 0];
        float4 a1 = proj4[(size_t)v.x * 4 + 1];
        float4 a2 = proj4[(size_t)v.x * 4 + 2];
        float4 a3 = proj4[(size_t)v.x * 4 + 3];
        float4 b0 = proj4[(size_t)v.y * 4 + 0];
        float4 b1 = proj4[(size_t)v.y * 4 + 1];
        float4 b2 = proj4[(size_t)v.y * 4 + 2];
        float4 b3 = proj4[(size_t)v.y * 4 + 3];
        float4 f0 = ef4[(size_t)e.x * 4 + 0];
        float4 f1 = ef4[(size_t)e.x * 4 + 1];
        float4 f2 = ef4[(size_t)e.x * 4 + 2];
        float4 f3 = ef4[(size_t)e.x * 4 + 3];
        float4 g0 = ef4[(size_t)e.y * 4 + 0];
        float4 g1 = ef4[(size_t)e.y * 4 + 1];
        float4 g2 = ef4[(size_t)e.y * 4 + 2];
        float4 g3 = ef4[(size_t)e.y * 4 + 3];
        double acc0 = (double)a0.x * f0.x + (double)a0.y * f0.y + (double)a0.z * f0.z + (double)a0.w * f0.w
                    + (double)a1.x * f1.x + (double)a1.y * f1.y + (double)a1.z * f1.z + (double)a1.w * f1.w
                    + (double)a2.x * f2.x + (double)a2.y * f2.y + (double)a2.z * f2.z + (double)a2.w * f2.w
                    + (double)a3.x * f3.x + (double)a3.y * f3.y + (double)a3.z * f3.z + (double)a3.w * f3.w;
        double acc1 = (double)b0.x * g0.x + (double)b0.y * g0.y + (double)b0.z * g0.z + (double)b0.w * g0.w
                    + (double)b1.x * g1.x + (double)b1.y * g1.y + (double)b1.z * g1.z + (double)b1.w * g1.w
                    + (double)b2.x * g2.x + (double)b2.y * g2.y + (double)b2.z * g2.z + (double)b2.w * g2.w
                    + (double)b3.x * g3.x + (double)b3.y * g3.y + (double)b3.z * g3.z + (double)b3.w * g3.w;
        float s0 = (float)(1.0 / (1.0 + exp(-acc0)));
        float s1 = (float)(1.0 / (1.0 + exp(-acc1)));
        scores2[i] = make_float2(s0, s1);
        unsigned bb0 = __float_as_uint(s0) >> 20;
        unsigned bb1 = __float_as_uint(s1) >> 20;
        if (bb0 == 1016) ++r1016; else if (bb0 == 1015) ++r1015;
        else if (bb0 == 0) ++r0; else atomicAdd(&h[bb0], 1u);
        if (bb1 == 1016) ++r1016; else if (bb1 == 1015) ++r1015;
        else if (bb1 == 0) ++r0; else atomicAdd(&h[bb1], 1u);
    }
    // odd tail element (one designated thread)
    if ((nnz & 1) && blockIdx.x == 0 && threadIdx.x == 0) {
        int i = nnz - 1;
        const int* Vi = (const int*)V2;
        const int* Ei = (const int*)E2;
        const float* pr = (const float*)proj4;
        const float* fr = (const float*)ef4;
        int v = Vi[i], e = Ei[i];
        double acc = 0.0;
        for (int r = 0; r < RANKK; ++r)
            acc += (double)pr[(size_t)v * RANKK + r] * (double)fr[(size_t)e * RANKK + r];
        float s = (float)(1.0 / (1.0 + exp(-acc)));
        ((float*)scores2)[i] = s;
        atomicAdd(&hist1g[__float_as_uint(s) >> 20], 1u);
    }
    if (r1016) atomicAdd(&h[1016], r1016);
    if (r1015) atomicAdd(&h[1015], r1015);
    if (r0) atomicAdd(&h[0], r0);
    __syncthreads();
    for (int t = threadIdx.x; t < 4096; t += 256)
        if (h[t]) atomicAdd(&hist1g[t], h[t]);
}

// ---------------- build bucket-ordered pairs (block-aggregated allocation) ----------------
#define PB_CHUNK 8192
__global__ __launch_bounds__(256) void pair_build(const int* __restrict__ E_idx,
        const float* __restrict__ scores, u64* __restrict__ pairs,
        unsigned* __restrict__ cursor, int nnz, int nb) {
    __shared__ unsigned bh[NBK_MAX];
    for (int t = threadIdx.x; t < NBK_MAX; t += 256) bh[t] = 0;
    __syncthreads();
    int base = blockIdx.x * PB_CHUNK;
    int nE = nnz - base;
    if (nE > PB_CHUNK) nE = PB_CHUNK;
    for (int o = threadIdx.x; o < nE; o += 256)
        atomicAdd(&bh[((unsigned)E_idx[base + o]) >> 8], 1u);
    __syncthreads();
    for (int b = threadIdx.x; b < nb; b += 256) {
        unsigned c = bh[b];
        bh[b] = c ? atomicAdd(&cursor[b], c) : 0u;
    }
    __syncthreads();
    for (int o = threadIdx.x; o < nE; o += 256) {
        int i = base + o;
        unsigned e = (unsigned)E_idx[i];
        unsigned bits = __float_as_uint(scores[i]);
        unsigned pos = atomicAdd(&bh[e >> 8], 1u);
        pairs[pos] = pack_pair(e & 255u, bits, (unsigned)i);
    }
}

// ---------------- parallel level-1 suffix scan (1 block) ----------------
__global__ void scan1_kernel(const unsigned* __restrict__ hist,
                             unsigned* __restrict__ sel, const int* __restrict__ kptr) {
    __shared__ unsigned sfx[256];
    int t = threadIdx.x;
    unsigned local[16];
    unsigned s = 0;
    #pragma unroll
    for (int j = 0; j < 16; ++j) { local[j] = hist[t * 16 + j]; s += local[j]; }
    sfx[t] = s;
    __syncthreads();
    for (int off = 1; off < 256; off <<= 1) {
        unsigned add = (t + off < 256) ? sfx[t + off] : 0;
        __syncthreads();
        sfx[t] += add;
        __syncthreads();
    }
    unsigned krem = (unsigned)(*kptr);
    unsigned above = (t + 1 < 256) ? sfx[t + 1] : 0;
    if (above < krem && sfx[t] >= krem) {
        unsigned cum = above;
        int b = t * 16;
        for (int j = 15; j >= 0; --j) {
            unsigned cc = local[j];
            if (cum + cc >= krem) { b = t * 16 + j; break; }
            cum += cc;
        }
        sel[0] = krem - cum;            // remaining k within bin b
        sel[1] = ((unsigned)b) << 20;   // 12-bit prefix
    }
}

// ---------------- compact candidates (from scores, 16 MB pass) ----------------
__global__ void compact_kernel(const float4* __restrict__ scores4,
                               const unsigned* __restrict__ sel,
                               uint2* __restrict__ cand, unsigned* __restrict__ candCount,
                               int n4, int nnz) {
    unsigned pref = sel[1] >> 20;
    int tid = blockIdx.x * blockDim.x + threadIdx.x;
    int stride = gridDim.x * blockDim.x;
    int lane = threadIdx.x & 63;
    int niter = (n4 + stride - 1) / stride;
    for (int kk = 0; kk < niter; ++kk) {
        int i = tid + kk * stride;
        bool inb = (i < n4);
        float4 sv = make_float4(0.f, 0.f, 0.f, 0.f);
        if (inb) sv = scores4[i];
        unsigned bb[4] = {__float_as_uint(sv.x), __float_as_uint(sv.y),
                          __float_as_uint(sv.z), __float_as_uint(sv.w)};
        #pragma unroll
        for (int q = 0; q < 4; ++q) {
            bool pred = inb && ((bb[q] >> 20) == pref);
            unsigned long long mask = __ballot(pred);
            if (mask) {
                int leader = __ffsll(mask) - 1;
                unsigned base = 0;
                if (lane == leader) base = atomicAdd(candCount, (unsigned)__popcll(mask));
                base = __shfl(base, leader, 64);
                if (pred) {
                    unsigned rank = __popcll(mask & ((1ull << lane) - 1ull));
                    unsigned pos = base + rank;
                    if (pos < CAND_CAP) cand[pos] = make_uint2(bb[q], (unsigned)(i * 4 + q));
                }
            }
        }
    }
    for (int i = n4 * 4 + tid; i < nnz; i += stride) {
        unsigned b = __float_as_uint(((const float*)scores4)[i]);
        if ((b >> 20) == pref) {
            unsigned pos = atomicAdd(candCount, 1u);
            if (pos < CAND_CAP) cand[pos] = make_uint2(b, (unsigned)i);
        }
    }
}

// ---------------- single-block selection among candidates ----------------
__global__ __launch_bounds__(256) void select_small(const uint2* __restrict__ cand,
                            const unsigned* __restrict__ candCount,
                            unsigned* __restrict__ sel, unsigned* __restrict__ tieList) {
    __shared__ unsigned h2[4096];
    __shared__ unsigned sfx[256];
    __shared__ unsigned sB2, sKrem2, sT, sM;
    __shared__ unsigned h3[256];
    __shared__ unsigned ties[TIE_CAP];
    __shared__ unsigned tcnt;
    int t = threadIdx.x;
    unsigned nc = *candCount;
    int n = (nc < CAND_CAP) ? (int)nc : CAND_CAP;
    unsigned krem = sel[0];
    unsigned pref = sel[1];

    for (int j = t; j < 4096; j += 256) h2[j] = 0;
    if (t == 0) tcnt = 0;
    __syncthreads();
    for (int j = t; j < n; j += 256) atomicAdd(&h2[(cand[j].x >> 8) & 0xFFF], 1u);
    __syncthreads();

    unsigned local[16];
    unsigned s = 0;
    #pragma unroll
    for (int j = 0; j < 16; ++j) { local[j] = h2[t * 16 + j]; s += local[j]; }
    sfx[t] = s;
    __syncthreads();
    for (int off = 1; off < 256; off <<= 1) {
        unsigned add = (t + off < 256) ? sfx[t + off] : 0;
        __syncthreads();
        sfx[t] += add;
        __syncthreads();
    }
    {
        unsigned above = (t + 1 < 256) ? sfx[t + 1] : 0;
        if (above < krem && sfx[t] >= krem) {
            unsigned cum = above;
            int b = t * 16;
            for (int j = 15; j >= 0; --j) {
                unsigned cc = local[j];
                if (cum + cc >= krem) { b = t * 16 + j; break; }
                cum += cc;
            }
            sB2 = (unsigned)b;
            sKrem2 = krem - cum;
        }
    }
    __syncthreads();

    h3[t] = 0;
    __syncthreads();
    unsigned b2 = sB2;
    for (int j = t; j < n; j += 256) {
        unsigned x = cand[j].x;
        if (((x >> 8) & 0xFFF) == b2) atomicAdd(&h3[x & 0xFF], 1u);
    }
    __syncthreads();
    sfx[t] = h3[t];
    __syncthreads();
    for (int off = 1; off < 256; off <<= 1) {
        unsigned add = (t + off < 256) ? sfx[t + off] : 0;
        __syncthreads();
        sfx[t] += add;
        __syncthreads();
    }
    {
        unsigned krem2 = sKrem2;
        unsigned above = (t + 1 < 256) ? sfx[t + 1] : 0;
        if (above < krem2 && sfx[t] >= krem2) {
            sT = pref | (b2 << 8) | (unsigned)t;
            sM = krem2 - above;
        }
    }
    __syncthreads();

    unsigned T = sT;
    for (int j = t; j < n; j += 256) {
        if (cand[j].x == T) {
            unsigned p = atomicAdd(&tcnt, 1u);
            if (p < TIE_CAP) ties[p] = cand[j].y;
        }
    }
    __syncthreads();
    if (t == 0) {
        unsigned cnt = (tcnt < TIE_CAP) ? tcnt : TIE_CAP;
        for (unsigned a = 1; a < cnt; ++a) {
            unsigned key = ties[a];
            int bpos = (int)a - 1;
            while (bpos >= 0 && ties[bpos] > key) { ties[bpos + 1] = ties[bpos]; --bpos; }
            ties[bpos + 1] = key;
        }
        unsigned m = sM;
        if (m > cnt) m = cnt;
        sel[2] = T;
        sel[3] = m;
        for (unsigned j = 0; j < m; ++j) tieList[j] = ties[j];
    }
}

// ---- fused per-bucket edge stats + finalize: eprob/esoft/ehard in ONE pairs pass ----
__global__ __launch_bounds__(256) void edge_final(const u64* __restrict__ pairs,
        const unsigned* __restrict__ bucketBase, const unsigned* __restrict__ sel,
        const unsigned* __restrict__ tieList,
        float* __restrict__ eprob, float* __restrict__ esoft, float* __restrict__ ehard,
        int nhe) {
    __shared__ float ss[256];
    __shared__ unsigned cc[256];
    __shared__ unsigned hh[256];
    __shared__ unsigned ties[TIE_CAP];
    unsigned T = sel[2];
    unsigned m = sel[3];
    if (m > TIE_CAP) m = TIE_CAP;
    int t = threadIdx.x;
    ss[t] = 0.f; cc[t] = 0u; hh[t] = 0u;
    for (int j = t; j < (int)m; j += 256) ties[j] = tieList[j];
    __syncthreads();
    int b = blockIdx.x;
    unsigned n0 = bucketBase[b], n1 = bucketBase[b + 1];
    for (unsigned j = n0 + t; j < n1; j += 256) {
        u64 p = pairs[j];
        unsigned el = (unsigned)(p >> 56);
        unsigned bits = (unsigned)(p >> 26) & 0x3FFFFFFFu;
        atomicAdd(&ss[el], __uint_as_float(bits));
        atomicAdd(&cc[el], 1u);
        bool keep = bits > T;
        if (bits == T) {
            unsigned idx = (unsigned)(p & 0x3FFFFFFu);
            int lo = 0, hi = (int)m - 1;
            keep = false;
            while (lo <= hi) {
                int mid = (lo + hi) >> 1;
                unsigned v = ties[mid];
                if (v == idx) { keep = true; break; }
                if (v < idx) lo = mid + 1; else hi = mid - 1;
            }
        }
        if (keep) atomicAdd(&hh[el], 1u);
    }
    __syncthreads();
    int e = b * 256 + t;
    if (e < nhe) {
        float c = fmaxf((float)cc[t], 1.0f);
        eprob[e] = ss[t] / c;
        esoft[e] = (float)hh[t] / c;
        ehard[e] = (hh[t] > 0) ? 1.0f : 0.0f;
    }
}

// ---------------- final classification: hard/soft (coalesced, no atomics) ----------------
__global__ __launch_bounds__(256) void write_hard(const float4* __restrict__ scores4,
                           const unsigned* __restrict__ sel,
                           const unsigned* __restrict__ tieList,
                           float4* __restrict__ hard4, float4* __restrict__ soft4,
                           int n4, int nnz) {
    __shared__ unsigned ties[TIE_CAP];
    unsigned T = sel[2];
    unsigned m = sel[3];
    if (m > TIE_CAP) m = TIE_CAP;
    for (int j = threadIdx.x; j < (int)m; j += blockDim.x) ties[j] = tieList[j];
    __syncthreads();
    int tid = blockIdx.x * blockDim.x + threadIdx.x;
    int stride = gridDim.x * blockDim.x;
    for (int i = tid; i < n4; i += stride) {
        float4 sv = scores4[i];
        unsigned bb[4] = {__float_as_uint(sv.x), __float_as_uint(sv.y),
                          __float_as_uint(sv.z), __float_as_uint(sv.w)};
        float hv[4];
        #pragma unroll
        for (int q = 0; q < 4; ++q) {
            bool keep = (bb[q] > T);
            if (bb[q] == T) {
                unsigned idx = (unsigned)(i * 4 + q);
                int lo = 0, hi = (int)m - 1;
                keep = false;
                while (lo <= hi) {
                    int mid = (lo + hi) >> 1;
                    unsigned v = ties[mid];
                    if (v == idx) { keep = true; break; }
                    if (v < idx) lo = mid + 1; else hi = mid - 1;
                }
            }
            hv[q] = keep ? 1.0f : 0.0f;
        }
        float4 outv = make_float4(hv[0], hv[1], hv[2], hv[3]);
        hard4[i] = outv;
        soft4[i] = outv;
    }
    const float* sc = (const float*)scores4;
    float* hard = (float*)hard4;
    float* soft = (float*)soft4;
    for (int i = n4 * 4 + tid; i < nnz; i += stride) {
        unsigned b = __float_as_uint(sc[i]);
        bool keep = (b > T);
        if (b == T) {
            unsigned idx = (unsigned)i;
            int lo = 0, hi = (int)m - 1;
            keep = false;
            while (lo <= hi) {
                int mid = (lo + hi) >> 1;
                unsigned v = ties[mid];
                if (v == idx) { keep = true; break; }
                if (v < idx) lo = mid + 1; else hi = mid - 1;
            }
        }
        float hvv = keep ? 1.0f : 0.0f;
        hard[i] = hvv;
        soft[i] = hvv;
    }
}

extern "C" void kernel_launch(void* const* d_in, const int* in_sizes, int n_in,
                              void* d_out, int out_size, void* d_ws, size_t ws_size,
                              hipStream_t stream) {
    const float* x        = (const float*)d_in[0];
    const float* Wm       = (const float*)d_in[1];
    const float* ef       = (const float*)d_in[2];
    const int*   V_idx    = (const int*)d_in[3];
    const int*   E_idx    = (const int*)d_in[4];
    const int*   edge_ids = (const int*)d_in[5];
    const int*   kptr     = (const int*)d_in[6];

    const int nnz     = in_sizes[3];
    const int nhe     = in_sizes[5];
    const int n_nodes = in_sizes[0] / FEAT;
    const int nb      = (nhe + 255) >> 8;   // buckets of 256 edges (<= NBK_MAX)

    float* out    = (float*)d_out;
    float* scores = out;
    float* soft   = out + (size_t)nnz;
    float* hard   = out + 2 * (size_t)nnz;
    float* eprob  = out + 3 * (size_t)nnz;
    float* esoft  = eprob + nhe;
    float* ehard  = esoft + nhe;

    // pairs live in soft+hard (exactly nnz u64); consumed by edge_final before write_hard.
    u64*   pairs = (u64*)soft;
    // cand lives in eprob region (1 MB <= 1.43 MB); consumed before edge_final writes eprob.
    uint2* cand  = (uint2*)eprob;

    // ---- aux zone in d_ws ----
    char* w = (char*)d_ws;
    unsigned* hist1      = (unsigned*)w;               // 4096
    unsigned* bucketCnt  = hist1 + 4096;               // NBK_MAX
    unsigned* candCount  = bucketCnt + NBK_MAX;        // 1
    unsigned* sel        = candCount + 1;              // 8
    unsigned* tieList    = sel + 8;                    // TIE_CAP
    unsigned* bucketBase = tieList + TIE_CAP;          // NBK_MAX+1
    unsigned* cursor     = bucketBase + NBK_MAX + 1;   // NBK_MAX
    char* auxEnd = (char*)(cursor + NBK_MAX);
    size_t auxAligned = (((size_t)(auxEnd - w)) + 255) & ~(size_t)255;

    size_t ef2Bytes  = (size_t)nhe * RANKK * sizeof(float);
    size_t projBytes = (size_t)n_nodes * RANKK * sizeof(float);

    float* ef2;
    float* proj;
    if (ws_size >= auxAligned + ef2Bytes + projBytes) {
        ef2  = (float*)(w + auxAligned);
        proj = (float*)(w + auxAligned + ef2Bytes);
    } else {
        // hard region (nnz floats >= ef2+proj): consumed by score_kernel,
        // which finishes before pair_build/write_hard touch hard.
        ef2  = hard;
        proj = hard + (size_t)nhe * RANKK;
    }

    // zero hist1 + bucketCnt + candCount (contiguous)
    hipMemsetAsync(w, 0, (size_t)(4096 + NBK_MAX + 1) * sizeof(unsigned), stream);

    ehist_kernel<<<128, 256, 0, stream>>>(E_idx, bucketCnt, nnz, nb);
    bucket_scan<<<1, NBK_MAX, 0, stream>>>(bucketCnt, bucketBase, cursor, nb, nnz);
    gather_ef<<<(nhe * 4 + 255) / 256, 256, 0, stream>>>(
        (const float4*)ef, edge_ids, (float4*)ef2, nhe);
    proj_kernel<<<(n_nodes + PRJ_NODES - 1) / PRJ_NODES, 256, 0, stream>>>(x, Wm, proj, n_nodes);

    int npair = nnz >> 1;
    score_kernel<<<2048, 256, 0, stream>>>(
        (const float4*)proj, (const float4*)ef2,
        (const int2*)V_idx, (const int2*)E_idx,
        (float2*)scores, hist1, npair, nnz);

    pair_build<<<(nnz + PB_CHUNK - 1) / PB_CHUNK, 256, 0, stream>>>(
        E_idx, scores, pairs, cursor, nnz, nb);

    int n4 = nnz / 4;
    scan1_kernel<<<1, 256, 0, stream>>>(hist1, sel, kptr);
    compact_kernel<<<1024, 256, 0, stream>>>(
        (const float4*)scores, sel, cand, candCount, n4, nnz);
    select_small<<<1, 256, 0, stream>>>(cand, candCount, sel, tieList);

    edge_final<<<nb, 256, 0, stream>>>(pairs, bucketBase, sel, tieList,
                                       eprob, esoft, ehard, nhe);
    write_hard<<<1024, 256, 0, stream>>>(
        (const float4*)scores, sel, tieList, (float4*)hard, (float4*)soft, n4, nnz);
}